// Round 1
// baseline (277.370 us; speedup 1.0000x reference)
//
#include <hip/hip_runtime.h>
#include <hip/hip_bf16.h>

// Problem constants
#define Bn   4
#define Cn   64
#define Hn   256
#define Wn   448
#define Gn   8                 // num_groups = C/8
#define CGn  8                 // channels per group
#define HWn  (Hn*Wn)           // 114688
#define CHWn (Cn*HWn)          // 7340032
#define NGn  (Bn*Gn)           // 32 (b,g) pairs
#define NBLKn 32               // row-chunks per (b,g) for stats partials
#define ROWS_PER_BLK (Hn/NBLKn)            // 8
#define ELEMS_PER_BLK (CGn*ROWS_PER_BLK*Wn) // 28672
#define VEC_PER_BLK  (ELEMS_PER_BLK/4)      // 7168 float4
#define VEC_PER_CHUNK ((ROWS_PER_BLK*Wn)/4) // 896 float4 per channel-chunk

// ws layout (float offsets)
#define WS_PART 0                          // 32*32*2 = 2048
#define WS_MEAN 2048                       // 32*2 = 64  (mean, rstd)
#define WS_RN   4096                       // B*HW = 458752
#define WS_SIM  (WS_RN + Bn*HWn)           // 462848, B*8*HW
#define WS_OFF  (WS_SIM + Bn*8*HWn)        // 4132864, B*2*HW
// total floats: 5050368 (~20.2 MB)

// ---------------- stats pass 1: per-(b,g,rowchunk) partial sum/sumsq ----------------
__global__ __launch_bounds__(256) void k_stats1(const float* __restrict__ x,
                                                float* __restrict__ ws) {
    const int bg  = blockIdx.x;       // 0..31
    const int blk = blockIdx.y;       // 0..31
    const int b = bg >> 3, g = bg & 7;
    const int r0 = blk * ROWS_PER_BLK;
    const float4* base = reinterpret_cast<const float4*>(
        x + (size_t)b*CHWn + (size_t)g*CGn*HWn + (size_t)r0*Wn);

    float s = 0.f, sq = 0.f;
    for (int i = threadIdx.x; i < VEC_PER_BLK; i += 256) {
        int ci  = i / VEC_PER_CHUNK;            // channel within group (0..7)
        int rem = i - ci*VEC_PER_CHUNK;
        float4 v = base[(size_t)ci*(HWn/4) + rem];
        s  += v.x + v.y + v.z + v.w;
        sq += v.x*v.x + v.y*v.y + v.z*v.z + v.w*v.w;
    }
    // block reduce (4 waves of 64)
    __shared__ float shs[4], shq[4];
    for (int o = 32; o > 0; o >>= 1) { s += __shfl_down(s, o); sq += __shfl_down(sq, o); }
    const int wid = threadIdx.x >> 6;
    if ((threadIdx.x & 63) == 0) { shs[wid] = s; shq[wid] = sq; }
    __syncthreads();
    if (threadIdx.x == 0) {
        s  = shs[0] + shs[1] + shs[2] + shs[3];
        sq = shq[0] + shq[1] + shq[2] + shq[3];
        ws[WS_PART + (bg*NBLKn + blk)*2 + 0] = s;
        ws[WS_PART + (bg*NBLKn + blk)*2 + 1] = sq;
    }
}

// ---------------- stats pass 2: combine partials -> mean, rstd ----------------
__global__ __launch_bounds__(64) void k_stats2(float* __restrict__ ws) {
    const int bg = blockIdx.x;
    const int t  = threadIdx.x;
    float s = 0.f, sq = 0.f;
    if (t < NBLKn) {
        s  = ws[WS_PART + (bg*NBLKn + t)*2 + 0];
        sq = ws[WS_PART + (bg*NBLKn + t)*2 + 1];
    }
    for (int o = 32; o > 0; o >>= 1) { s += __shfl_down(s, o); sq += __shfl_down(sq, o); }
    if (t == 0) {
        const float n = (float)(CGn*HWn);
        float mean = s / n;
        float var  = sq / n - mean*mean;
        ws[WS_MEAN + bg*2 + 0] = mean;
        ws[WS_MEAN + bg*2 + 1] = 1.0f / sqrtf(var + 1e-5f);
    }
}

// helper: load per-channel affine (scale, shift) into LDS. b uniform per block.
__device__ __forceinline__ void load_affine(const float* __restrict__ ws,
                                            const float* __restrict__ wgt,
                                            const float* __restrict__ bias,
                                            int b, float* sc, float* sh) {
    if (threadIdx.x < Cn) {
        int c = threadIdx.x;
        float mean = ws[WS_MEAN + (b*Gn + (c >> 3))*2 + 0];
        float rstd = ws[WS_MEAN + (b*Gn + (c >> 3))*2 + 1];
        float s = rstd * wgt[c];
        sc[c] = s;
        sh[c] = bias[c] - mean * s;
    }
    __syncthreads();
}

// ---------------- reciprocal norm map ----------------
__global__ __launch_bounds__(256) void k_rnorm(const float* __restrict__ x,
                                               const float* __restrict__ wgt,
                                               const float* __restrict__ bias,
                                               float* __restrict__ ws) {
    __shared__ float sc[Cn], sh[Cn];
    const int p = blockIdx.x*256 + threadIdx.x;   // 0..B*HW-1
    const int b = p / HWn;
    const int r = p - b*HWn;
    load_affine(ws, wgt, bias, b, sc, sh);

    const float* px = x + (size_t)b*CHWn + r;
    float acc = 0.f;
    #pragma unroll 8
    for (int c = 0; c < Cn; ++c) {
        float v = px[(size_t)c*HWn] * sc[c] + sh[c];
        acc += v*v;
    }
    float nrm = fmaxf(sqrtf(acc), 1e-8f);
    ws[WS_RN + p] = 1.0f / nrm;
}

// ---------------- cosine similarity map (8 dilated neighbors) ----------------
__global__ __launch_bounds__(256) void k_sim(const float* __restrict__ x,
                                             const float* __restrict__ wgt,
                                             const float* __restrict__ bias,
                                             float* __restrict__ ws) {
    __shared__ float sc[Cn], sh[Cn];
    const int b  = blockIdx.z;
    const int tw = threadIdx.x & 63, th = threadIdx.x >> 6;
    const int w  = blockIdx.x*64 + tw;
    const int h  = blockIdx.y*4  + th;
    load_affine(ws, wgt, bias, b, sc, sh);

    const int dyv[8] = {-2,-2,-2, 0, 0, 2, 2, 2};
    const int dxv[8] = {-2, 0, 2,-2, 2,-2, 0, 2};
    bool inb[8]; int off[8];
    #pragma unroll
    for (int k = 0; k < 8; ++k) {
        int hn = h + dyv[k], wn = w + dxv[k];
        inb[k] = (hn >= 0) & (hn < Hn) & (wn >= 0) & (wn < Wn);
        off[k] = dyv[k]*Wn + dxv[k];
    }

    const float* px = x + (size_t)b*CHWn + (size_t)h*Wn + w;
    float dot[8] = {0,0,0,0,0,0,0,0};
    #pragma unroll 4
    for (int c = 0; c < Cn; ++c) {
        const float* pc = px + (size_t)c*HWn;
        float xc = pc[0] * sc[c] + sh[c];
        #pragma unroll
        for (int k = 0; k < 8; ++k) {
            if (inb[k]) {
                float xn = pc[off[k]] * sc[c] + sh[c];
                dot[k] += xc * xn;
            }
        }
    }
    const float rnc = ws[WS_RN + (size_t)b*HWn + h*Wn + w];
    #pragma unroll
    for (int k = 0; k < 8; ++k) {
        float s = 0.f;
        if (inb[k]) {
            float rnn = ws[WS_RN + (size_t)b*HWn + (h + dyv[k])*Wn + (w + dxv[k])];
            s = dot[k] * rnc * rnn;
        }
        ws[WS_SIM + ((size_t)(b*8 + k))*HWn + h*Wn + w] = s;
    }
}

// ---------------- two 3x3 convs (8->2) + sigmoid gate -> offset ----------------
__global__ __launch_bounds__(256) void k_conv(const float* __restrict__ ow,
                                              const float* __restrict__ obias,
                                              const float* __restrict__ sw,
                                              const float* __restrict__ sbias,
                                              float* __restrict__ ws) {
    __shared__ float wo[2*8*9], wg[2*8*9];
    for (int i = threadIdx.x; i < 144; i += 256) { wo[i] = ow[i]; wg[i] = sw[i]; }
    __syncthreads();

    const int p = blockIdx.x*256 + threadIdx.x;
    const int b = p / HWn;
    const int r = p - b*HWn;
    const int h = r / Wn;
    const int w = r - h*Wn;

    float ao0 = obias[0], ao1 = obias[1], as0 = sbias[0], as1 = sbias[1];
    const float* simb = ws + WS_SIM + (size_t)b*8*HWn;
    for (int kc = 0; kc < 8; ++kc) {
        const float* sp = simb + (size_t)kc*HWn;
        #pragma unroll
        for (int dy = -1; dy <= 1; ++dy) {
            int hh = h + dy;
            #pragma unroll
            for (int dx = -1; dx <= 1; ++dx) {
                int wwp = w + dx;
                float v = 0.f;
                if (hh >= 0 && hh < Hn && wwp >= 0 && wwp < Wn) v = sp[hh*Wn + wwp];
                int wi = kc*9 + (dy+1)*3 + (dx+1);
                ao0 += wo[wi      ] * v;
                ao1 += wo[wi + 72 ] * v;
                as0 += wg[wi      ] * v;
                as1 += wg[wi + 72 ] * v;
            }
        }
    }
    float o0 = ao0 * (1.0f / (1.0f + expf(-as0)));
    float o1 = ao1 * (1.0f / (1.0f + expf(-as1)));
    ws[WS_OFF + ((size_t)b*2 + 0)*HWn + r] = o0;
    ws[WS_OFF + ((size_t)b*2 + 1)*HWn + r] = o1;
}

// ---------------- nearest-sample of group-normed features ----------------
__global__ __launch_bounds__(256) void k_sample(const float* __restrict__ x,
                                                const float* __restrict__ wgt,
                                                const float* __restrict__ bias,
                                                const float* __restrict__ ws,
                                                float* __restrict__ out) {
    __shared__ float sc[Cn], sh[Cn];
    const int p = blockIdx.x*256 + threadIdx.x;
    const int b = p / HWn;
    const int r = p - b*HWn;
    const int h = r / Wn;
    const int w = r - h*Wn;
    load_affine(ws, wgt, bias, b, sc, sh);

    const float off0 = ws[WS_OFF + ((size_t)b*2 + 0)*HWn + r];
    const float off1 = ws[WS_OFF + ((size_t)b*2 + 1)*HWn + r];

    // replicate reference arithmetic exactly (f32)
    float gx  = ((float)w + 0.5f) + off0;
    float gy  = ((float)h + 0.5f) + off1;
    float ngx = 2.0f*gx/(float)Wn - 1.0f;
    float ngy = 2.0f*gy/(float)Hn - 1.0f;
    float fx  = ((ngx + 1.0f)*(float)Wn - 1.0f)*0.5f;
    float fy  = ((ngy + 1.0f)*(float)Hn - 1.0f)*0.5f;
    int ix = (int)fminf(fmaxf(rintf(fx), 0.f), (float)(Wn-1));
    int iy = (int)fminf(fmaxf(rintf(fy), 0.f), (float)(Hn-1));

    const float* px = x + (size_t)b*CHWn + (size_t)iy*Wn + ix;
    float* po = out + (size_t)b*CHWn + r;
    #pragma unroll 8
    for (int c = 0; c < Cn; ++c) {
        po[(size_t)c*HWn] = px[(size_t)c*HWn] * sc[c] + sh[c];
    }
}

extern "C" void kernel_launch(void* const* d_in, const int* in_sizes, int n_in,
                              void* d_out, int out_size, void* d_ws, size_t ws_size,
                              hipStream_t stream) {
    const float* x     = (const float*)d_in[0];  // aligned_feat
    // d_in[1] original_feat, d_in[2] flow: unused by reference
    const float* wgt   = (const float*)d_in[3];  // gn_weight
    const float* bias  = (const float*)d_in[4];  // gn_bias
    const float* ow    = (const float*)d_in[5];  // offset_w (2,8,3,3)
    const float* ob    = (const float*)d_in[6];  // offset_b (2,)
    const float* sw    = (const float*)d_in[7];  // scale_w
    const float* sb    = (const float*)d_in[8];  // scale_b
    float* out = (float*)d_out;
    float* ws  = (float*)d_ws;

    k_stats1<<<dim3(NGn, NBLKn), 256, 0, stream>>>(x, ws);
    k_stats2<<<NGn, 64, 0, stream>>>(ws);
    k_rnorm <<<(Bn*HWn)/256, 256, 0, stream>>>(x, wgt, bias, ws);
    k_sim   <<<dim3(Wn/64, Hn/4, Bn), 256, 0, stream>>>(x, wgt, bias, ws);
    k_conv  <<<(Bn*HWn)/256, 256, 0, stream>>>(ow, ob, sw, sb, ws);
    k_sample<<<(Bn*HWn)/256, 256, 0, stream>>>(x, wgt, bias, ws, out);
}

// Round 2
// 123.995 us; speedup vs baseline: 2.2369x; 2.2369x over previous
//
#include <hip/hip_runtime.h>
#include <hip/hip_bf16.h>

// Problem constants
#define Bn   4
#define Cn   64
#define Hn   256
#define Wn   448
#define Gn   8                 // num_groups = C/8
#define CGn  8                 // channels per group
#define HWn  (Hn*Wn)           // 114688
#define CHWn (Cn*HWn)          // 7340032
#define NGn  (Bn*Gn)           // 32 (b,g) pairs
#define NBLKn 32               // row-chunks per (b,g) for stats partials
#define ROWS_PER_BLK (Hn/NBLKn)            // 8
#define ELEMS_PER_BLK (CGn*ROWS_PER_BLK*Wn) // 28672
#define VEC_PER_BLK  (ELEMS_PER_BLK/4)      // 7168 float4
#define VEC_PER_CHUNK ((ROWS_PER_BLK*Wn)/4) // 896 float4 per channel-chunk

// ws layout (float offsets)
#define WS_PART 0                          // 32*32*2 = 2048
#define WS_MEAN 2048                       // 32*2 = 64  (mean, rstd)
#define WS_RN   4096                       // (unused since r2, kept for layout)
#define WS_SIM  (WS_RN + Bn*HWn)           // B*8*HW
#define WS_OFF  (WS_SIM + Bn*8*HWn)        // B*2*HW

// ---------------- stats pass 1: per-(b,g,rowchunk) partial sum/sumsq ----------------
__global__ __launch_bounds__(256) void k_stats1(const float* __restrict__ x,
                                                float* __restrict__ ws) {
    const int bg  = blockIdx.x;       // 0..31
    const int blk = blockIdx.y;       // 0..31
    const int b = bg >> 3, g = bg & 7;
    const int r0 = blk * ROWS_PER_BLK;
    const float4* base = reinterpret_cast<const float4*>(
        x + (size_t)b*CHWn + (size_t)g*CGn*HWn + (size_t)r0*Wn);

    float s = 0.f, sq = 0.f;
    for (int i = threadIdx.x; i < VEC_PER_BLK; i += 256) {
        int ci  = i / VEC_PER_CHUNK;            // channel within group (0..7)
        int rem = i - ci*VEC_PER_CHUNK;
        float4 v = base[(size_t)ci*(HWn/4) + rem];
        s  += v.x + v.y + v.z + v.w;
        sq += v.x*v.x + v.y*v.y + v.z*v.z + v.w*v.w;
    }
    __shared__ float shs[4], shq[4];
    for (int o = 32; o > 0; o >>= 1) { s += __shfl_down(s, o); sq += __shfl_down(sq, o); }
    const int wid = threadIdx.x >> 6;
    if ((threadIdx.x & 63) == 0) { shs[wid] = s; shq[wid] = sq; }
    __syncthreads();
    if (threadIdx.x == 0) {
        s  = shs[0] + shs[1] + shs[2] + shs[3];
        sq = shq[0] + shq[1] + shq[2] + shq[3];
        ws[WS_PART + (bg*NBLKn + blk)*2 + 0] = s;
        ws[WS_PART + (bg*NBLKn + blk)*2 + 1] = sq;
    }
}

// ---------------- stats pass 2: combine partials -> mean, rstd ----------------
__global__ __launch_bounds__(64) void k_stats2(float* __restrict__ ws) {
    const int bg = blockIdx.x;
    const int t  = threadIdx.x;
    float s = 0.f, sq = 0.f;
    if (t < NBLKn) {
        s  = ws[WS_PART + (bg*NBLKn + t)*2 + 0];
        sq = ws[WS_PART + (bg*NBLKn + t)*2 + 1];
    }
    for (int o = 32; o > 0; o >>= 1) { s += __shfl_down(s, o); sq += __shfl_down(sq, o); }
    if (t == 0) {
        const float n = (float)(CGn*HWn);
        float mean = s / n;
        float var  = sq / n - mean*mean;
        ws[WS_MEAN + bg*2 + 0] = mean;
        ws[WS_MEAN + bg*2 + 1] = 1.0f / sqrtf(var + 1e-5f);
    }
}

// helper: load per-channel affine (scale, shift) into LDS. b uniform per block.
__device__ __forceinline__ void load_affine(const float* __restrict__ ws,
                                            const float* __restrict__ wgt,
                                            const float* __restrict__ bias,
                                            int b, float* sc, float* sh) {
    if (threadIdx.x < Cn) {
        int c = threadIdx.x;
        float mean = ws[WS_MEAN + (b*Gn + (c >> 3))*2 + 0];
        float rstd = ws[WS_MEAN + (b*Gn + (c >> 3))*2 + 1];
        float s = rstd * wgt[c];
        sc[c] = s;
        sh[c] = bias[c] - mean * s;
    }
    __syncthreads();
}

// ---------------- fused norm + cosine similarity, LDS-tiled ----------------
// Tile: 16 rows x 64 cols of output pixels. Staged halo tile: 20 rows x 72 cols
// (float4-aligned window [w0-4, w0+68)), zero-padded outside the image.
// Per channel: stage tile (double-buffered, reg-prefetched), each thread
// computes 8-direction dot partials for its 4 consecutive pixels from LDS.
// Norm^2 per staged cell accumulated in the owning thread's registers.
#define S_R4 18                 // float4 per staged row
#define S_ROWS 20
#define NSTG (S_ROWS*S_R4)      // 360 staged float4

__global__ __launch_bounds__(256) void k_sim2(const float* __restrict__ x,
                                              const float* __restrict__ wgt,
                                              const float* __restrict__ bias,
                                              float* __restrict__ ws) {
    __shared__ float sc[Cn], sh[Cn];
    __shared__ float4 tile[2][NSTG];
    __shared__ float4 n2s[NSTG];

    // XCD-chunked swizzle: 448 blocks, 56 consecutive (h-adjacent) per XCD
    int lin = blockIdx.x;
    int nid = (lin & 7) * 56 + (lin >> 3);
    int b   = nid / 112;
    int rem = nid - b*112;
    int th_ = rem / 7;
    int tw_ = rem - th_*7;
    const int h0 = th_*16, w0 = tw_*64;

    load_affine(ws, wgt, bias, b, sc, sh);

    const int tid = threadIdx.x;
    // staging ownership: cell i = (row, c4), i in {tid, tid+256} (i<360)
    const int r0c = tid / S_R4, c40 = tid - r0c*S_R4;
    const int i1  = tid + 256;
    const bool has1 = (i1 < NSTG);
    const int r1c = i1 / S_R4, c41 = i1 - r1c*S_R4;

    const int gr0 = h0 - 2 + r0c, gc0 = (w0 >> 2) - 1 + c40;
    const bool val0 = (gr0 >= 0) & (gr0 < Hn) & (gc0 >= 0) & (gc0 < (Wn/4));
    const int gr1 = h0 - 2 + r1c, gc1 = (w0 >> 2) - 1 + c41;
    const bool val1 = has1 & (gr1 >= 0) & (gr1 < Hn) & (gc1 >= 0) & (gc1 < (Wn/4));

    const float4* xb = reinterpret_cast<const float4*>(x + (size_t)b*CHWn);
    const size_t HW4 = HWn/4;
    const size_t off0 = val0 ? ((size_t)gr0*(Wn/4) + gc0) : 0;
    const size_t off1 = val1 ? ((size_t)gr1*(Wn/4) + gc1) : 0;

    // compute mapping: 4 consecutive pixels per thread
    const int prow = tid >> 4;          // 0..15
    const int pc4  = tid & 15;          // 0..15

    float dot[4][8];
    #pragma unroll
    for (int j = 0; j < 4; ++j)
        #pragma unroll
        for (int k = 0; k < 8; ++k) dot[j][k] = 0.f;

    float4 a0 = {0,0,0,0}, a1 = {0,0,0,0};

    // prefetch channel 0
    float4 ra = xb[off0];
    float4 rb = xb[off1];

    int buf = 0;
    #pragma unroll 2
    for (int c = 0; c < Cn; ++c) {
        const float s = sc[c], t = sh[c];
        float4 wv0, wv1;
        wv0.x = val0 ? ra.x*s + t : 0.f;
        wv0.y = val0 ? ra.y*s + t : 0.f;
        wv0.z = val0 ? ra.z*s + t : 0.f;
        wv0.w = val0 ? ra.w*s + t : 0.f;
        wv1.x = val1 ? rb.x*s + t : 0.f;
        wv1.y = val1 ? rb.y*s + t : 0.f;
        wv1.z = val1 ? rb.z*s + t : 0.f;
        wv1.w = val1 ? rb.w*s + t : 0.f;
        tile[buf][r0c*S_R4 + c40] = wv0;
        if (has1) tile[buf][r1c*S_R4 + c41] = wv1;
        a0.x += wv0.x*wv0.x; a0.y += wv0.y*wv0.y; a0.z += wv0.z*wv0.z; a0.w += wv0.w*wv0.w;
        a1.x += wv1.x*wv1.x; a1.y += wv1.y*wv1.y; a1.z += wv1.z*wv1.z; a1.w += wv1.w*wv1.w;
        if (c < Cn-1) {
            ra = xb[(size_t)(c+1)*HW4 + off0];
            rb = xb[(size_t)(c+1)*HW4 + off1];
        }
        __syncthreads();

        const float4* tb = tile[buf];
        float4 m0 = tb[(prow  )*S_R4 + pc4], m1 = tb[(prow  )*S_R4 + pc4+1], m2 = tb[(prow  )*S_R4 + pc4+2];
        float4 z0 = tb[(prow+2)*S_R4 + pc4], z1 = tb[(prow+2)*S_R4 + pc4+1], z2 = tb[(prow+2)*S_R4 + pc4+2];
        float4 p0 = tb[(prow+4)*S_R4 + pc4], p1 = tb[(prow+4)*S_R4 + pc4+1], p2 = tb[(prow+4)*S_R4 + pc4+2];
        float vm[12] = {m0.x,m0.y,m0.z,m0.w, m1.x,m1.y,m1.z,m1.w, m2.x,m2.y,m2.z,m2.w};
        float vz[12] = {z0.x,z0.y,z0.z,z0.w, z1.x,z1.y,z1.z,z1.w, z2.x,z2.y,z2.z,z2.w};
        float vp[12] = {p0.x,p0.y,p0.z,p0.w, p1.x,p1.y,p1.z,p1.w, p2.x,p2.y,p2.z,p2.w};
        #pragma unroll
        for (int j = 0; j < 4; ++j) {
            float xc = vz[4+j];
            dot[j][0] += xc*vm[2+j];
            dot[j][1] += xc*vm[4+j];
            dot[j][2] += xc*vm[6+j];
            dot[j][3] += xc*vz[2+j];
            dot[j][4] += xc*vz[6+j];
            dot[j][5] += xc*vp[2+j];
            dot[j][6] += xc*vp[4+j];
            dot[j][7] += xc*vp[6+j];
        }
        buf ^= 1;
    }

    // dump norm^2 cells, then scale dots -> sims
    n2s[r0c*S_R4 + c40] = a0;
    if (has1) n2s[r1c*S_R4 + c41] = a1;
    __syncthreads();

    {
        const float4* nb = n2s;
        float4 m0 = nb[(prow  )*S_R4 + pc4], m1 = nb[(prow  )*S_R4 + pc4+1], m2 = nb[(prow  )*S_R4 + pc4+2];
        float4 z0 = nb[(prow+2)*S_R4 + pc4], z1 = nb[(prow+2)*S_R4 + pc4+1], z2 = nb[(prow+2)*S_R4 + pc4+2];
        float4 p0 = nb[(prow+4)*S_R4 + pc4], p1 = nb[(prow+4)*S_R4 + pc4+1], p2 = nb[(prow+4)*S_R4 + pc4+2];
        float nm[12] = {m0.x,m0.y,m0.z,m0.w, m1.x,m1.y,m1.z,m1.w, m2.x,m2.y,m2.z,m2.w};
        float nz[12] = {z0.x,z0.y,z0.z,z0.w, z1.x,z1.y,z1.z,z1.w, z2.x,z2.y,z2.z,z2.w};
        float np_[12]= {p0.x,p0.y,p0.z,p0.w, p1.x,p1.y,p1.z,p1.w, p2.x,p2.y,p2.z,p2.w};
        // reciprocal norms for window elements 2..9 of each row
        float rm[8], rz[8], rp[8];
        #pragma unroll
        for (int e = 0; e < 8; ++e) {
            rm[e] = 1.0f / fmaxf(sqrtf(nm[2+e]), 1e-8f);
            rz[e] = 1.0f / fmaxf(sqrtf(nz[2+e]), 1e-8f);
            rp[e] = 1.0f / fmaxf(sqrtf(np_[2+e]), 1e-8f);
        }
        float* simb = ws + WS_SIM + (size_t)b*8*HWn + (size_t)(h0+prow)*Wn + (w0 + pc4*4);
        #pragma unroll
        for (int k = 0; k < 8; ++k) {
            float4 o;
            #pragma unroll
            for (int j = 0; j < 4; ++j) {
                float rnc = rz[2+j];
                float rnn;
                switch (k) {
                    case 0: rnn = rm[j];   break;
                    case 1: rnn = rm[2+j]; break;
                    case 2: rnn = rm[4+j]; break;
                    case 3: rnn = rz[j];   break;
                    case 4: rnn = rz[4+j]; break;
                    case 5: rnn = rp[j];   break;
                    case 6: rnn = rp[2+j]; break;
                    default: rnn = rp[4+j]; break;
                }
                float v = dot[j][k]*rnc*rnn;
                if (j == 0) o.x = v; else if (j == 1) o.y = v; else if (j == 2) o.z = v; else o.w = v;
            }
            *reinterpret_cast<float4*>(simb + (size_t)k*HWn) = o;
        }
    }
}

// ---------------- two 3x3 convs (8->2) + sigmoid gate -> offset ----------------
__global__ __launch_bounds__(256) void k_conv(const float* __restrict__ ow,
                                              const float* __restrict__ obias,
                                              const float* __restrict__ sw,
                                              const float* __restrict__ sbias,
                                              float* __restrict__ ws) {
    __shared__ float wo[2*8*9], wg[2*8*9];
    for (int i = threadIdx.x; i < 144; i += 256) { wo[i] = ow[i]; wg[i] = sw[i]; }
    __syncthreads();

    const int p = blockIdx.x*256 + threadIdx.x;
    const int b = p / HWn;
    const int r = p - b*HWn;
    const int h = r / Wn;
    const int w = r - h*Wn;

    float ao0 = obias[0], ao1 = obias[1], as0 = sbias[0], as1 = sbias[1];
    const float* simb = ws + WS_SIM + (size_t)b*8*HWn;
    for (int kc = 0; kc < 8; ++kc) {
        const float* sp = simb + (size_t)kc*HWn;
        #pragma unroll
        for (int dy = -1; dy <= 1; ++dy) {
            int hh = h + dy;
            #pragma unroll
            for (int dx = -1; dx <= 1; ++dx) {
                int wwp = w + dx;
                float v = 0.f;
                if (hh >= 0 && hh < Hn && wwp >= 0 && wwp < Wn) v = sp[hh*Wn + wwp];
                int wi = kc*9 + (dy+1)*3 + (dx+1);
                ao0 += wo[wi      ] * v;
                ao1 += wo[wi + 72 ] * v;
                as0 += wg[wi      ] * v;
                as1 += wg[wi + 72 ] * v;
            }
        }
    }
    float o0 = ao0 * (1.0f / (1.0f + expf(-as0)));
    float o1 = ao1 * (1.0f / (1.0f + expf(-as1)));
    ws[WS_OFF + ((size_t)b*2 + 0)*HWn + r] = o0;
    ws[WS_OFF + ((size_t)b*2 + 1)*HWn + r] = o1;
}

// ---------------- nearest-sample of group-normed features ----------------
__global__ __launch_bounds__(256) void k_sample(const float* __restrict__ x,
                                                const float* __restrict__ wgt,
                                                const float* __restrict__ bias,
                                                const float* __restrict__ ws,
                                                float* __restrict__ out) {
    __shared__ float sc[Cn], sh[Cn];
    const int p = blockIdx.x*256 + threadIdx.x;
    const int b = p / HWn;
    const int r = p - b*HWn;
    const int h = r / Wn;
    const int w = r - h*Wn;
    load_affine(ws, wgt, bias, b, sc, sh);

    const float off0 = ws[WS_OFF + ((size_t)b*2 + 0)*HWn + r];
    const float off1 = ws[WS_OFF + ((size_t)b*2 + 1)*HWn + r];

    // replicate reference arithmetic exactly (f32)
    float gx  = ((float)w + 0.5f) + off0;
    float gy  = ((float)h + 0.5f) + off1;
    float ngx = 2.0f*gx/(float)Wn - 1.0f;
    float ngy = 2.0f*gy/(float)Hn - 1.0f;
    float fx  = ((ngx + 1.0f)*(float)Wn - 1.0f)*0.5f;
    float fy  = ((ngy + 1.0f)*(float)Hn - 1.0f)*0.5f;
    int ix = (int)fminf(fmaxf(rintf(fx), 0.f), (float)(Wn-1));
    int iy = (int)fminf(fmaxf(rintf(fy), 0.f), (float)(Hn-1));

    const float* px = x + (size_t)b*CHWn + (size_t)iy*Wn + ix;
    float* po = out + (size_t)b*CHWn + r;
    #pragma unroll 8
    for (int c = 0; c < Cn; ++c) {
        po[(size_t)c*HWn] = px[(size_t)c*HWn] * sc[c] + sh[c];
    }
}

extern "C" void kernel_launch(void* const* d_in, const int* in_sizes, int n_in,
                              void* d_out, int out_size, void* d_ws, size_t ws_size,
                              hipStream_t stream) {
    const float* x     = (const float*)d_in[0];  // aligned_feat
    const float* wgt   = (const float*)d_in[3];  // gn_weight
    const float* bias  = (const float*)d_in[4];  // gn_bias
    const float* ow    = (const float*)d_in[5];  // offset_w (2,8,3,3)
    const float* ob    = (const float*)d_in[6];  // offset_b (2,)
    const float* sw    = (const float*)d_in[7];  // scale_w
    const float* sb    = (const float*)d_in[8];  // scale_b
    float* out = (float*)d_out;
    float* ws  = (float*)d_ws;

    k_stats1<<<dim3(NGn, NBLKn), 256, 0, stream>>>(x, ws);
    k_stats2<<<NGn, 64, 0, stream>>>(ws);
    k_sim2  <<<448, 256, 0, stream>>>(x, wgt, bias, ws);
    k_conv  <<<(Bn*HWn)/256, 256, 0, stream>>>(ow, ob, sw, sb, ws);
    k_sample<<<(Bn*HWn)/256, 256, 0, stream>>>(x, wgt, bias, ws, out);
}

// Round 5
// 112.686 us; speedup vs baseline: 2.4614x; 1.1004x over previous
//
#include <hip/hip_runtime.h>
#include <hip/hip_bf16.h>

// Problem constants
#define Bn   4
#define Cn   64
#define Hn   256
#define Wn   448
#define Gn   8                 // num_groups = C/8
#define CGn  8                 // channels per group
#define HWn  (Hn*Wn)           // 114688
#define CHWn (Cn*HWn)          // 7340032
#define NGn  (Bn*Gn)           // 32 (b,g) pairs
#define NBLKn 32               // row-chunks per (b,g) for stats partials
#define ROWS_PER_BLK (Hn/NBLKn)            // 8
#define ELEMS_PER_BLK (CGn*ROWS_PER_BLK*Wn) // 28672
#define VEC_PER_BLK  (ELEMS_PER_BLK/4)      // 7168 float4
#define VEC_PER_CHUNK ((ROWS_PER_BLK*Wn)/4) // 896 float4 per channel-chunk

typedef float f32x4 __attribute__((ext_vector_type(4)));

// ws layout (float offsets)
#define WS_PART 0                          // 32*32*2 = 2048
#define WS_MEAN 2048                       // 32*2 = 64  (mean, rstd)
#define WS_RN   4096                       // (unused, kept for layout stability)
#define WS_SIM  (WS_RN + Bn*HWn)           // B*8*HW

// ---------------- stats pass 1: per-(b,g,rowchunk) partial sum/sumsq ----------------
__global__ __launch_bounds__(256) void k_stats1(const float* __restrict__ x,
                                                float* __restrict__ ws) {
    const int bg  = blockIdx.x;       // 0..31
    const int blk = blockIdx.y;       // 0..31
    const int b = bg >> 3, g = bg & 7;
    const int r0 = blk * ROWS_PER_BLK;
    const float4* base = reinterpret_cast<const float4*>(
        x + (size_t)b*CHWn + (size_t)g*CGn*HWn + (size_t)r0*Wn);

    float s = 0.f, sq = 0.f;
    for (int i = threadIdx.x; i < VEC_PER_BLK; i += 256) {
        int ci  = i / VEC_PER_CHUNK;            // channel within group (0..7)
        int rem = i - ci*VEC_PER_CHUNK;
        float4 v = base[(size_t)ci*(HWn/4) + rem];
        s  += v.x + v.y + v.z + v.w;
        sq += v.x*v.x + v.y*v.y + v.z*v.z + v.w*v.w;
    }
    __shared__ float shs[4], shq[4];
    for (int o = 32; o > 0; o >>= 1) { s += __shfl_down(s, o); sq += __shfl_down(sq, o); }
    const int wid = threadIdx.x >> 6;
    if ((threadIdx.x & 63) == 0) { shs[wid] = s; shq[wid] = sq; }
    __syncthreads();
    if (threadIdx.x == 0) {
        s  = shs[0] + shs[1] + shs[2] + shs[3];
        sq = shq[0] + shq[1] + shq[2] + shq[3];
        ws[WS_PART + (bg*NBLKn + blk)*2 + 0] = s;
        ws[WS_PART + (bg*NBLKn + blk)*2 + 1] = sq;
    }
}

// ---------------- stats pass 2: combine partials -> mean, rstd ----------------
__global__ __launch_bounds__(64) void k_stats2(float* __restrict__ ws) {
    const int bg = blockIdx.x;
    const int t  = threadIdx.x;
    float s = 0.f, sq = 0.f;
    if (t < NBLKn) {
        s  = ws[WS_PART + (bg*NBLKn + t)*2 + 0];
        sq = ws[WS_PART + (bg*NBLKn + t)*2 + 1];
    }
    for (int o = 32; o > 0; o >>= 1) { s += __shfl_down(s, o); sq += __shfl_down(sq, o); }
    if (t == 0) {
        const float n = (float)(CGn*HWn);
        float mean = s / n;
        float var  = sq / n - mean*mean;
        ws[WS_MEAN + bg*2 + 0] = mean;
        ws[WS_MEAN + bg*2 + 1] = 1.0f / sqrtf(var + 1e-5f);
    }
}

// helper: load per-channel affine (scale, shift) into LDS. b uniform per block.
__device__ __forceinline__ void load_affine(const float* __restrict__ ws,
                                            const float* __restrict__ wgt,
                                            const float* __restrict__ bias,
                                            int b, float* sc, float* sh) {
    if (threadIdx.x < Cn) {
        int c = threadIdx.x;
        float mean = ws[WS_MEAN + (b*Gn + (c >> 3))*2 + 0];
        float rstd = ws[WS_MEAN + (b*Gn + (c >> 3))*2 + 1];
        float s = rstd * wgt[c];
        sc[c] = s;
        sh[c] = bias[c] - mean * s;
    }
    __syncthreads();
}

// ---------------- fused norm + cosine similarity, LDS-tiled ----------------
#define S_R4 18                 // float4 per staged row
#define S_ROWS 20
#define NSTG (S_ROWS*S_R4)      // 360 staged float4

__global__ __launch_bounds__(256) void k_sim2(const float* __restrict__ x,
                                              const float* __restrict__ wgt,
                                              const float* __restrict__ bias,
                                              float* __restrict__ ws) {
    __shared__ float sc[Cn], sh[Cn];
    __shared__ float4 tile[2][NSTG];
    __shared__ float4 n2s[NSTG];

    // XCD-chunked swizzle: 448 blocks, 56 consecutive (h-adjacent) per XCD
    int lin = blockIdx.x;
    int nid = (lin & 7) * 56 + (lin >> 3);
    int b   = nid / 112;
    int rem = nid - b*112;
    int th_ = rem / 7;
    int tw_ = rem - th_*7;
    const int h0 = th_*16, w0 = tw_*64;

    load_affine(ws, wgt, bias, b, sc, sh);

    const int tid = threadIdx.x;
    const int r0c = tid / S_R4, c40 = tid - r0c*S_R4;
    const int i1  = tid + 256;
    const bool has1 = (i1 < NSTG);
    const int r1c = i1 / S_R4, c41 = i1 - r1c*S_R4;

    const int gr0 = h0 - 2 + r0c, gc0 = (w0 >> 2) - 1 + c40;
    const bool val0 = (gr0 >= 0) & (gr0 < Hn) & (gc0 >= 0) & (gc0 < (Wn/4));
    const int gr1 = h0 - 2 + r1c, gc1 = (w0 >> 2) - 1 + c41;
    const bool val1 = has1 & (gr1 >= 0) & (gr1 < Hn) & (gc1 >= 0) & (gc1 < (Wn/4));

    const float4* xb = reinterpret_cast<const float4*>(x + (size_t)b*CHWn);
    const size_t HW4 = HWn/4;
    const size_t off0 = val0 ? ((size_t)gr0*(Wn/4) + gc0) : 0;
    const size_t off1 = val1 ? ((size_t)gr1*(Wn/4) + gc1) : 0;

    const int prow = tid >> 4;          // 0..15
    const int pc4  = tid & 15;          // 0..15

    float dot[4][8];
    #pragma unroll
    for (int j = 0; j < 4; ++j)
        #pragma unroll
        for (int k = 0; k < 8; ++k) dot[j][k] = 0.f;

    float4 a0 = {0,0,0,0}, a1 = {0,0,0,0};

    float4 ra = xb[off0];
    float4 rb = xb[off1];

    int buf = 0;
    #pragma unroll 2
    for (int c = 0; c < Cn; ++c) {
        const float s = sc[c], t = sh[c];
        float4 wv0, wv1;
        wv0.x = val0 ? ra.x*s + t : 0.f;
        wv0.y = val0 ? ra.y*s + t : 0.f;
        wv0.z = val0 ? ra.z*s + t : 0.f;
        wv0.w = val0 ? ra.w*s + t : 0.f;
        wv1.x = val1 ? rb.x*s + t : 0.f;
        wv1.y = val1 ? rb.y*s + t : 0.f;
        wv1.z = val1 ? rb.z*s + t : 0.f;
        wv1.w = val1 ? rb.w*s + t : 0.f;
        tile[buf][r0c*S_R4 + c40] = wv0;
        if (has1) tile[buf][r1c*S_R4 + c41] = wv1;
        a0.x += wv0.x*wv0.x; a0.y += wv0.y*wv0.y; a0.z += wv0.z*wv0.z; a0.w += wv0.w*wv0.w;
        a1.x += wv1.x*wv1.x; a1.y += wv1.y*wv1.y; a1.z += wv1.z*wv1.z; a1.w += wv1.w*wv1.w;
        if (c < Cn-1) {
            ra = xb[(size_t)(c+1)*HW4 + off0];
            rb = xb[(size_t)(c+1)*HW4 + off1];
        }
        __syncthreads();

        const float4* tb = tile[buf];
        float4 m0 = tb[(prow  )*S_R4 + pc4], m1 = tb[(prow  )*S_R4 + pc4+1], m2 = tb[(prow  )*S_R4 + pc4+2];
        float4 z0 = tb[(prow+2)*S_R4 + pc4], z1 = tb[(prow+2)*S_R4 + pc4+1], z2 = tb[(prow+2)*S_R4 + pc4+2];
        float4 p0 = tb[(prow+4)*S_R4 + pc4], p1 = tb[(prow+4)*S_R4 + pc4+1], p2 = tb[(prow+4)*S_R4 + pc4+2];
        float vm[12] = {m0.x,m0.y,m0.z,m0.w, m1.x,m1.y,m1.z,m1.w, m2.x,m2.y,m2.z,m2.w};
        float vz[12] = {z0.x,z0.y,z0.z,z0.w, z1.x,z1.y,z1.z,z1.w, z2.x,z2.y,z2.z,z2.w};
        float vp[12] = {p0.x,p0.y,p0.z,p0.w, p1.x,p1.y,p1.z,p1.w, p2.x,p2.y,p2.z,p2.w};
        #pragma unroll
        for (int j = 0; j < 4; ++j) {
            float xc = vz[4+j];
            dot[j][0] += xc*vm[2+j];
            dot[j][1] += xc*vm[4+j];
            dot[j][2] += xc*vm[6+j];
            dot[j][3] += xc*vz[2+j];
            dot[j][4] += xc*vz[6+j];
            dot[j][5] += xc*vp[2+j];
            dot[j][6] += xc*vp[4+j];
            dot[j][7] += xc*vp[6+j];
        }
        buf ^= 1;
    }

    n2s[r0c*S_R4 + c40] = a0;
    if (has1) n2s[r1c*S_R4 + c41] = a1;
    __syncthreads();

    {
        const float4* nb = n2s;
        float4 m0 = nb[(prow  )*S_R4 + pc4], m1 = nb[(prow  )*S_R4 + pc4+1], m2 = nb[(prow  )*S_R4 + pc4+2];
        float4 z0 = nb[(prow+2)*S_R4 + pc4], z1 = nb[(prow+2)*S_R4 + pc4+1], z2 = nb[(prow+2)*S_R4 + pc4+2];
        float4 p0 = nb[(prow+4)*S_R4 + pc4], p1 = nb[(prow+4)*S_R4 + pc4+1], p2 = nb[(prow+4)*S_R4 + pc4+2];
        float nm[12] = {m0.x,m0.y,m0.z,m0.w, m1.x,m1.y,m1.z,m1.w, m2.x,m2.y,m2.z,m2.w};
        float nz[12] = {z0.x,z0.y,z0.z,z0.w, z1.x,z1.y,z1.z,z1.w, z2.x,z2.y,z2.z,z2.w};
        float np_[12]= {p0.x,p0.y,p0.z,p0.w, p1.x,p1.y,p1.z,p1.w, p2.x,p2.y,p2.z,p2.w};
        float rm[8], rz[8], rp[8];
        #pragma unroll
        for (int e = 0; e < 8; ++e) {
            rm[e] = 1.0f / fmaxf(sqrtf(nm[2+e]), 1e-8f);
            rz[e] = 1.0f / fmaxf(sqrtf(nz[2+e]), 1e-8f);
            rp[e] = 1.0f / fmaxf(sqrtf(np_[2+e]), 1e-8f);
        }
        float* simb = ws + WS_SIM + (size_t)b*8*HWn + (size_t)(h0+prow)*Wn + (w0 + pc4*4);
        #pragma unroll
        for (int k = 0; k < 8; ++k) {
            f32x4 o;
            #pragma unroll
            for (int j = 0; j < 4; ++j) {
                float rnc = rz[2+j];
                float rnn;
                switch (k) {
                    case 0: rnn = rm[j];   break;
                    case 1: rnn = rm[2+j]; break;
                    case 2: rnn = rm[4+j]; break;
                    case 3: rnn = rz[j];   break;
                    case 4: rnn = rz[4+j]; break;
                    case 5: rnn = rp[j];   break;
                    case 6: rnn = rp[2+j]; break;
                    default: rnn = rp[4+j]; break;
                }
                o[j] = dot[j][k]*rnc*rnn;
            }
            __builtin_nontemporal_store(o, reinterpret_cast<f32x4*>(simb + (size_t)k*HWn));
        }
    }
}

// ---------------- fused: 3x3 convs + sigmoid gate + nearest-sample + out ----------------
// One thread = 4 consecutive pixels (1 float4 column group).
__global__ __launch_bounds__(256) void k_csamp(const float* __restrict__ x,
                                               const float* __restrict__ wgt,
                                               const float* __restrict__ bias,
                                               const float* __restrict__ ow,
                                               const float* __restrict__ obias,
                                               const float* __restrict__ sw,
                                               const float* __restrict__ sbias,
                                               const float* __restrict__ ws,
                                               float* __restrict__ out) {
    __shared__ float sc[Cn], sh[Cn];
    __shared__ float wo[144], wg[144];

    const int u  = blockIdx.x*256 + threadIdx.x;   // f4 index in [0, B*HW/4)
    const int b  = u / (HWn/4);
    const int r4 = u - b*(HWn/4);
    const int h  = r4 / (Wn/4);
    const int j  = r4 - h*(Wn/4);                  // f4 col 0..111

    load_affine(ws, wgt, bias, b, sc, sh);         // includes one __syncthreads
    for (int i = threadIdx.x; i < 144; i += 256) { wo[i] = ow[i]; wg[i] = sw[i]; }
    __syncthreads();

    float ao0[4], ao1[4], as0[4], as1[4];
    {
        const float b0 = obias[0], b1 = obias[1], c0 = sbias[0], c1 = sbias[1];
        #pragma unroll
        for (int p = 0; p < 4; ++p) { ao0[p] = b0; ao1[p] = b1; as0[p] = c0; as1[p] = c1; }
    }

    const float* simb = ws + WS_SIM + (size_t)b*8*HWn;
    #pragma unroll 2
    for (int kc = 0; kc < 8; ++kc) {
        const float* sp = simb + (size_t)kc*HWn;
        #pragma unroll
        for (int dy = -1; dy <= 1; ++dy) {
            const int hh = h + dy;
            const bool rowok = (hh >= 0) & (hh < Hn);
            const float* rowp = sp + (size_t)hh*Wn;
            float4 Bv = {0,0,0,0};
            float Aw = 0.f, Cx = 0.f;
            if (rowok) {
                Bv = reinterpret_cast<const float4*>(rowp)[j];
                if (j > 0)   Aw = rowp[4*j - 1];
                if (j < 111) Cx = rowp[4*j + 4];
            }
            float win[6] = {Aw, Bv.x, Bv.y, Bv.z, Bv.w, Cx};
            const int wi = kc*9 + (dy+1)*3;
            const float w00 = wo[wi], w01 = wo[wi+1], w02 = wo[wi+2];
            const float w10 = wo[wi+72], w11 = wo[wi+73], w12 = wo[wi+74];
            const float g00 = wg[wi], g01 = wg[wi+1], g02 = wg[wi+2];
            const float g10 = wg[wi+72], g11 = wg[wi+73], g12 = wg[wi+74];
            #pragma unroll
            for (int p = 0; p < 4; ++p) {
                const float t0 = win[p], t1 = win[p+1], t2 = win[p+2];
                ao0[p] += w00*t0 + w01*t1 + w02*t2;
                ao1[p] += w10*t0 + w11*t1 + w12*t2;
                as0[p] += g00*t0 + g01*t1 + g02*t2;
                as1[p] += g10*t0 + g11*t1 + g12*t2;
            }
        }
    }

    // offsets -> nearest indices (exact reference arithmetic, f32)
    int ixs[4], iys[4];
    #pragma unroll
    for (int p = 0; p < 4; ++p) {
        const float o0 = ao0[p] * (1.0f / (1.0f + expf(-as0[p])));
        const float o1 = ao1[p] * (1.0f / (1.0f + expf(-as1[p])));
        const int w = 4*j + p;
        float gx  = ((float)w + 0.5f) + o0;
        float gy  = ((float)h + 0.5f) + o1;
        float ngx = 2.0f*gx/(float)Wn - 1.0f;
        float ngy = 2.0f*gy/(float)Hn - 1.0f;
        float fx  = ((ngx + 1.0f)*(float)Wn - 1.0f)*0.5f;
        float fy  = ((ngy + 1.0f)*(float)Hn - 1.0f)*0.5f;
        ixs[p] = (int)fminf(fmaxf(rintf(fx), 0.f), (float)(Wn-1));
        iys[p] = (int)fminf(fmaxf(rintf(fy), 0.f), (float)(Hn-1));
    }
    const int base0 = iys[0]*Wn + ixs[0];
    const int base1 = iys[1]*Wn + ixs[1];
    const int base2 = iys[2]*Wn + ixs[2];
    const int base3 = iys[3]*Wn + ixs[3];

    const float* xb = x + (size_t)b*CHWn;
    float* po = out + (size_t)b*CHWn + (size_t)h*Wn + 4*j;
    #pragma unroll 4
    for (int c = 0; c < Cn; ++c) {
        const float* pc = xb + (size_t)c*HWn;
        const float s = sc[c], t = sh[c];
        f32x4 o;
        o[0] = pc[base0]*s + t;
        o[1] = pc[base1]*s + t;
        o[2] = pc[base2]*s + t;
        o[3] = pc[base3]*s + t;
        __builtin_nontemporal_store(o, reinterpret_cast<f32x4*>(po + (size_t)c*HWn));
    }
}

extern "C" void kernel_launch(void* const* d_in, const int* in_sizes, int n_in,
                              void* d_out, int out_size, void* d_ws, size_t ws_size,
                              hipStream_t stream) {
    const float* x     = (const float*)d_in[0];  // aligned_feat
    const float* wgt   = (const float*)d_in[3];  // gn_weight
    const float* bias  = (const float*)d_in[4];  // gn_bias
    const float* ow    = (const float*)d_in[5];  // offset_w (2,8,3,3)
    const float* ob    = (const float*)d_in[6];  // offset_b (2,)
    const float* sw    = (const float*)d_in[7];  // scale_w
    const float* sb    = (const float*)d_in[8];  // scale_b
    float* out = (float*)d_out;
    float* ws  = (float*)d_ws;

    k_stats1<<<dim3(NGn, NBLKn), 256, 0, stream>>>(x, ws);
    k_stats2<<<NGn, 64, 0, stream>>>(ws);
    k_sim2  <<<448, 256, 0, stream>>>(x, wgt, bias, ws);
    k_csamp <<<(Bn*HWn/4)/256, 256, 0, stream>>>(x, wgt, bias, ow, ob, sw, sb, ws, out);
}

// Round 6
// 110.754 us; speedup vs baseline: 2.5044x; 1.0174x over previous
//
#include <hip/hip_runtime.h>
#include <hip/hip_bf16.h>

// Problem constants
#define Bn   4
#define Cn   64
#define Hn   256
#define Wn   448
#define Gn   8                 // num_groups = C/8
#define CGn  8                 // channels per group
#define HWn  (Hn*Wn)           // 114688
#define CHWn (Cn*HWn)          // 7340032
#define NGn  (Bn*Gn)           // 32 (b,g) pairs
#define NBLKn 32               // row-chunks per (b,g) for stats partials
#define ROWS_PER_BLK (Hn/NBLKn)            // 8
#define ELEMS_PER_BLK (CGn*ROWS_PER_BLK*Wn) // 28672
#define VEC_PER_BLK  (ELEMS_PER_BLK/4)      // 7168 float4
#define VEC_PER_CHUNK ((ROWS_PER_BLK*Wn)/4) // 896 float4 per channel-chunk

typedef float f32x4 __attribute__((ext_vector_type(4)));

// ws layout (float offsets)
#define WS_PART 0                          // 32*32*2 = 2048
#define WS_MEAN 2048                       // 32*2 = 64  (mean, rstd)
#define WS_RN   4096                       // (unused, kept for layout stability)
#define WS_SIM  (WS_RN + Bn*HWn)           // B*8*HW

// ---------------- stats pass 1: per-(b,g,rowchunk) partial sum/sumsq ----------------
__global__ __launch_bounds__(256) void k_stats1(const float* __restrict__ x,
                                                float* __restrict__ ws) {
    const int bg  = blockIdx.x;       // 0..31
    const int blk = blockIdx.y;       // 0..31
    const int b = bg >> 3, g = bg & 7;
    const int r0 = blk * ROWS_PER_BLK;
    const float4* base = reinterpret_cast<const float4*>(
        x + (size_t)b*CHWn + (size_t)g*CGn*HWn + (size_t)r0*Wn);

    float s = 0.f, sq = 0.f;
    for (int i = threadIdx.x; i < VEC_PER_BLK; i += 256) {
        int ci  = i / VEC_PER_CHUNK;            // channel within group (0..7)
        int rem = i - ci*VEC_PER_CHUNK;
        float4 v = base[(size_t)ci*(HWn/4) + rem];
        s  += v.x + v.y + v.z + v.w;
        sq += v.x*v.x + v.y*v.y + v.z*v.z + v.w*v.w;
    }
    __shared__ float shs[4], shq[4];
    for (int o = 32; o > 0; o >>= 1) { s += __shfl_down(s, o); sq += __shfl_down(sq, o); }
    const int wid = threadIdx.x >> 6;
    if ((threadIdx.x & 63) == 0) { shs[wid] = s; shq[wid] = sq; }
    __syncthreads();
    if (threadIdx.x == 0) {
        s  = shs[0] + shs[1] + shs[2] + shs[3];
        sq = shq[0] + shq[1] + shq[2] + shq[3];
        ws[WS_PART + (bg*NBLKn + blk)*2 + 0] = s;
        ws[WS_PART + (bg*NBLKn + blk)*2 + 1] = sq;
    }
}

// ---------------- stats pass 2: combine partials -> mean, rstd ----------------
__global__ __launch_bounds__(64) void k_stats2(float* __restrict__ ws) {
    const int bg = blockIdx.x;
    const int t  = threadIdx.x;
    float s = 0.f, sq = 0.f;
    if (t < NBLKn) {
        s  = ws[WS_PART + (bg*NBLKn + t)*2 + 0];
        sq = ws[WS_PART + (bg*NBLKn + t)*2 + 1];
    }
    for (int o = 32; o > 0; o >>= 1) { s += __shfl_down(s, o); sq += __shfl_down(sq, o); }
    if (t == 0) {
        const float n = (float)(CGn*HWn);
        float mean = s / n;
        float var  = sq / n - mean*mean;
        ws[WS_MEAN + bg*2 + 0] = mean;
        ws[WS_MEAN + bg*2 + 1] = 1.0f / sqrtf(var + 1e-5f);
    }
}

// helper: load per-channel affine (scale, shift) into LDS. b uniform per block.
__device__ __forceinline__ void load_affine(const float* __restrict__ ws,
                                            const float* __restrict__ wgt,
                                            const float* __restrict__ bias,
                                            int b, float* sc, float* sh) {
    if (threadIdx.x < Cn) {
        int c = threadIdx.x;
        float mean = ws[WS_MEAN + (b*Gn + (c >> 3))*2 + 0];
        float rstd = ws[WS_MEAN + (b*Gn + (c >> 3))*2 + 1];
        float s = rstd * wgt[c];
        sc[c] = s;
        sh[c] = bias[c] - mean * s;
    }
    __syncthreads();
}

// ---------------- fused norm + cosine similarity, LDS-tiled ----------------
#define S_R4 18                 // float4 per staged row
#define S_ROWS 20
#define NSTG (S_ROWS*S_R4)      // 360 staged float4

// One channel step: consume prefetched regs RA/RB, stage into TB, accumulate
// norm^2, issue depth-2 prefetch for channel C+2, barrier, accumulate dots.
#define STAGE_STEP(C, RA, RB, TB)                                              \
    {                                                                          \
        const float s_ = sc[(C)], t_ = sh[(C)];                                \
        float4 wv0, wv1;                                                       \
        wv0.x = val0 ? RA.x*s_ + t_ : 0.f;                                     \
        wv0.y = val0 ? RA.y*s_ + t_ : 0.f;                                     \
        wv0.z = val0 ? RA.z*s_ + t_ : 0.f;                                     \
        wv0.w = val0 ? RA.w*s_ + t_ : 0.f;                                     \
        wv1.x = val1 ? RB.x*s_ + t_ : 0.f;                                     \
        wv1.y = val1 ? RB.y*s_ + t_ : 0.f;                                     \
        wv1.z = val1 ? RB.z*s_ + t_ : 0.f;                                     \
        wv1.w = val1 ? RB.w*s_ + t_ : 0.f;                                     \
        TB[r0c*S_R4 + c40] = wv0;                                              \
        if (has1) TB[r1c*S_R4 + c41] = wv1;                                    \
        a0.x += wv0.x*wv0.x; a0.y += wv0.y*wv0.y;                              \
        a0.z += wv0.z*wv0.z; a0.w += wv0.w*wv0.w;                              \
        a1.x += wv1.x*wv1.x; a1.y += wv1.y*wv1.y;                              \
        a1.z += wv1.z*wv1.z; a1.w += wv1.w*wv1.w;                              \
        if ((C) + 2 < Cn) {                                                    \
            RA = xb[(size_t)((C)+2)*HW4 + off0];                               \
            RB = xb[(size_t)((C)+2)*HW4 + off1];                               \
        }                                                                      \
        __syncthreads();                                                       \
        const float4* tb = TB;                                                 \
        float4 m0 = tb[(prow  )*S_R4 + pc4], m1 = tb[(prow  )*S_R4 + pc4+1],   \
               m2 = tb[(prow  )*S_R4 + pc4+2];                                 \
        float4 z0 = tb[(prow+2)*S_R4 + pc4], z1 = tb[(prow+2)*S_R4 + pc4+1],   \
               z2 = tb[(prow+2)*S_R4 + pc4+2];                                 \
        float4 p0 = tb[(prow+4)*S_R4 + pc4], p1 = tb[(prow+4)*S_R4 + pc4+1],   \
               p2 = tb[(prow+4)*S_R4 + pc4+2];                                 \
        float vm[12] = {m0.x,m0.y,m0.z,m0.w, m1.x,m1.y,m1.z,m1.w,              \
                        m2.x,m2.y,m2.z,m2.w};                                  \
        float vz[12] = {z0.x,z0.y,z0.z,z0.w, z1.x,z1.y,z1.z,z1.w,              \
                        z2.x,z2.y,z2.z,z2.w};                                  \
        float vp[12] = {p0.x,p0.y,p0.z,p0.w, p1.x,p1.y,p1.z,p1.w,              \
                        p2.x,p2.y,p2.z,p2.w};                                  \
        _Pragma("unroll")                                                      \
        for (int j = 0; j < 4; ++j) {                                          \
            float xc = vz[4+j];                                                \
            dot[j][0] += xc*vm[2+j];                                           \
            dot[j][1] += xc*vm[4+j];                                           \
            dot[j][2] += xc*vm[6+j];                                           \
            dot[j][3] += xc*vz[2+j];                                           \
            dot[j][4] += xc*vz[6+j];                                           \
            dot[j][5] += xc*vp[2+j];                                           \
            dot[j][6] += xc*vp[4+j];                                           \
            dot[j][7] += xc*vp[6+j];                                           \
        }                                                                      \
    }

__global__ __launch_bounds__(256) void k_sim2(const float* __restrict__ x,
                                              const float* __restrict__ wgt,
                                              const float* __restrict__ bias,
                                              float* __restrict__ ws) {
    __shared__ float sc[Cn], sh[Cn];
    __shared__ float4 tile[2][NSTG];
    __shared__ float4 n2s[NSTG];

    // XCD-chunked swizzle: 448 blocks, 56 consecutive (h-adjacent) per XCD
    int lin = blockIdx.x;
    int nid = (lin & 7) * 56 + (lin >> 3);
    int b   = nid / 112;
    int rem = nid - b*112;
    int th_ = rem / 7;
    int tw_ = rem - th_*7;
    const int h0 = th_*16, w0 = tw_*64;

    load_affine(ws, wgt, bias, b, sc, sh);

    const int tid = threadIdx.x;
    const int r0c = tid / S_R4, c40 = tid - r0c*S_R4;
    const int i1  = tid + 256;
    const bool has1 = (i1 < NSTG);
    const int r1c = i1 / S_R4, c41 = i1 - r1c*S_R4;

    const int gr0 = h0 - 2 + r0c, gc0 = (w0 >> 2) - 1 + c40;
    const bool val0 = (gr0 >= 0) & (gr0 < Hn) & (gc0 >= 0) & (gc0 < (Wn/4));
    const int gr1 = h0 - 2 + r1c, gc1 = (w0 >> 2) - 1 + c41;
    const bool val1 = has1 & (gr1 >= 0) & (gr1 < Hn) & (gc1 >= 0) & (gc1 < (Wn/4));

    const float4* xb = reinterpret_cast<const float4*>(x + (size_t)b*CHWn);
    const size_t HW4 = HWn/4;
    const size_t off0 = val0 ? ((size_t)gr0*(Wn/4) + gc0) : 0;
    const size_t off1 = val1 ? ((size_t)gr1*(Wn/4) + gc1) : 0;

    const int prow = tid >> 4;          // 0..15
    const int pc4  = tid & 15;          // 0..15

    float dot[4][8];
    #pragma unroll
    for (int j = 0; j < 4; ++j)
        #pragma unroll
        for (int k = 0; k < 8; ++k) dot[j][k] = 0.f;

    float4 a0 = {0,0,0,0}, a1 = {0,0,0,0};

    // depth-2 prefetch: channels 0 and 1 in flight before the loop
    float4 pa0 = xb[off0],        pb0 = xb[off1];
    float4 pa1 = xb[HW4 + off0],  pb1 = xb[HW4 + off1];

    for (int cc = 0; cc < Cn; cc += 2) {
        STAGE_STEP(cc,     pa0, pb0, tile[0]);
        STAGE_STEP(cc + 1, pa1, pb1, tile[1]);
    }

    n2s[r0c*S_R4 + c40] = a0;
    if (has1) n2s[r1c*S_R4 + c41] = a1;
    __syncthreads();

    {
        const float4* nb = n2s;
        float4 m0 = nb[(prow  )*S_R4 + pc4], m1 = nb[(prow  )*S_R4 + pc4+1], m2 = nb[(prow  )*S_R4 + pc4+2];
        float4 z0 = nb[(prow+2)*S_R4 + pc4], z1 = nb[(prow+2)*S_R4 + pc4+1], z2 = nb[(prow+2)*S_R4 + pc4+2];
        float4 p0 = nb[(prow+4)*S_R4 + pc4], p1 = nb[(prow+4)*S_R4 + pc4+1], p2 = nb[(prow+4)*S_R4 + pc4+2];
        float nm[12] = {m0.x,m0.y,m0.z,m0.w, m1.x,m1.y,m1.z,m1.w, m2.x,m2.y,m2.z,m2.w};
        float nz[12] = {z0.x,z0.y,z0.z,z0.w, z1.x,z1.y,z1.z,z1.w, z2.x,z2.y,z2.z,z2.w};
        float np_[12]= {p0.x,p0.y,p0.z,p0.w, p1.x,p1.y,p1.z,p1.w, p2.x,p2.y,p2.z,p2.w};
        float rm[8], rz[8], rp[8];
        #pragma unroll
        for (int e = 0; e < 8; ++e) {
            rm[e] = 1.0f / fmaxf(sqrtf(nm[2+e]), 1e-8f);
            rz[e] = 1.0f / fmaxf(sqrtf(nz[2+e]), 1e-8f);
            rp[e] = 1.0f / fmaxf(sqrtf(np_[2+e]), 1e-8f);
        }
        float* simb = ws + WS_SIM + (size_t)b*8*HWn + (size_t)(h0+prow)*Wn + (w0 + pc4*4);
        #pragma unroll
        for (int k = 0; k < 8; ++k) {
            f32x4 o;
            #pragma unroll
            for (int j = 0; j < 4; ++j) {
                float rnc = rz[2+j];
                float rnn;
                switch (k) {
                    case 0: rnn = rm[j];   break;
                    case 1: rnn = rm[2+j]; break;
                    case 2: rnn = rm[4+j]; break;
                    case 3: rnn = rz[j];   break;
                    case 4: rnn = rz[4+j]; break;
                    case 5: rnn = rp[j];   break;
                    case 6: rnn = rp[2+j]; break;
                    default: rnn = rp[4+j]; break;
                }
                o[j] = dot[j][k]*rnc*rnn;
            }
            // regular store: sim is re-read by k_csamp, keep it cache-resident
            *reinterpret_cast<f32x4*>(simb + (size_t)k*HWn) = o;
        }
    }
}

// ---------------- fused: 3x3 convs + sigmoid gate + nearest-sample + out ----------------
// One thread = 4 consecutive pixels (1 float4 column group).
__global__ __launch_bounds__(256) void k_csamp(const float* __restrict__ x,
                                               const float* __restrict__ wgt,
                                               const float* __restrict__ bias,
                                               const float* __restrict__ ow,
                                               const float* __restrict__ obias,
                                               const float* __restrict__ sw,
                                               const float* __restrict__ sbias,
                                               const float* __restrict__ ws,
                                               float* __restrict__ out) {
    __shared__ float sc[Cn], sh[Cn];
    __shared__ float wo[144], wg[144];

    const int u  = blockIdx.x*256 + threadIdx.x;   // f4 index in [0, B*HW/4)
    const int b  = u / (HWn/4);
    const int r4 = u - b*(HWn/4);
    const int h  = r4 / (Wn/4);
    const int j  = r4 - h*(Wn/4);                  // f4 col 0..111

    load_affine(ws, wgt, bias, b, sc, sh);         // includes one __syncthreads
    for (int i = threadIdx.x; i < 144; i += 256) { wo[i] = ow[i]; wg[i] = sw[i]; }
    __syncthreads();

    float ao0[4], ao1[4], as0[4], as1[4];
    {
        const float b0 = obias[0], b1 = obias[1], c0 = sbias[0], c1 = sbias[1];
        #pragma unroll
        for (int p = 0; p < 4; ++p) { ao0[p] = b0; ao1[p] = b1; as0[p] = c0; as1[p] = c1; }
    }

    const float* simb = ws + WS_SIM + (size_t)b*8*HWn;
    #pragma unroll 2
    for (int kc = 0; kc < 8; ++kc) {
        const float* sp = simb + (size_t)kc*HWn;
        #pragma unroll
        for (int dy = -1; dy <= 1; ++dy) {
            const int hh = h + dy;
            const bool rowok = (hh >= 0) & (hh < Hn);
            const float* rowp = sp + (size_t)hh*Wn;
            float4 Bv = {0,0,0,0};
            float Aw = 0.f, Cx = 0.f;
            if (rowok) {
                Bv = reinterpret_cast<const float4*>(rowp)[j];
                if (j > 0)   Aw = rowp[4*j - 1];
                if (j < 111) Cx = rowp[4*j + 4];
            }
            float win[6] = {Aw, Bv.x, Bv.y, Bv.z, Bv.w, Cx};
            const int wi = kc*9 + (dy+1)*3;
            const float w00 = wo[wi], w01 = wo[wi+1], w02 = wo[wi+2];
            const float w10 = wo[wi+72], w11 = wo[wi+73], w12 = wo[wi+74];
            const float g00 = wg[wi], g01 = wg[wi+1], g02 = wg[wi+2];
            const float g10 = wg[wi+72], g11 = wg[wi+73], g12 = wg[wi+74];
            #pragma unroll
            for (int p = 0; p < 4; ++p) {
                const float t0 = win[p], t1 = win[p+1], t2 = win[p+2];
                ao0[p] += w00*t0 + w01*t1 + w02*t2;
                ao1[p] += w10*t0 + w11*t1 + w12*t2;
                as0[p] += g00*t0 + g01*t1 + g02*t2;
                as1[p] += g10*t0 + g11*t1 + g12*t2;
            }
        }
    }

    // offsets -> nearest indices (exact reference arithmetic, f32)
    int ixs[4], iys[4];
    #pragma unroll
    for (int p = 0; p < 4; ++p) {
        const float o0 = ao0[p] * (1.0f / (1.0f + expf(-as0[p])));
        const float o1 = ao1[p] * (1.0f / (1.0f + expf(-as1[p])));
        const int w = 4*j + p;
        float gx  = ((float)w + 0.5f) + o0;
        float gy  = ((float)h + 0.5f) + o1;
        float ngx = 2.0f*gx/(float)Wn - 1.0f;
        float ngy = 2.0f*gy/(float)Hn - 1.0f;
        float fx  = ((ngx + 1.0f)*(float)Wn - 1.0f)*0.5f;
        float fy  = ((ngy + 1.0f)*(float)Hn - 1.0f)*0.5f;
        ixs[p] = (int)fminf(fmaxf(rintf(fx), 0.f), (float)(Wn-1));
        iys[p] = (int)fminf(fmaxf(rintf(fy), 0.f), (float)(Hn-1));
    }

    const float* xb = x + (size_t)b*CHWn;
    float* po = out + (size_t)b*CHWn + (size_t)h*Wn + 4*j;

    // Fast path: all 4 gather indices equal this thread's own float4 cell
    // (the common case for tiny offsets) -> coalesced float4 loads.
    const bool fast = (iys[0]==h) & (ixs[0]==4*j  ) &
                      (iys[1]==h) & (ixs[1]==4*j+1) &
                      (iys[2]==h) & (ixs[2]==4*j+2) &
                      (iys[3]==h) & (ixs[3]==4*j+3);
    if (fast) {
        const size_t o = (size_t)h*Wn + 4*j;
        #pragma unroll 8
        for (int c = 0; c < Cn; ++c) {
            const f32x4 v = *reinterpret_cast<const f32x4*>(xb + (size_t)c*HWn + o);
            const float s = sc[c], t = sh[c];
            f32x4 ov;
            ov[0] = v[0]*s + t; ov[1] = v[1]*s + t;
            ov[2] = v[2]*s + t; ov[3] = v[3]*s + t;
            __builtin_nontemporal_store(ov, reinterpret_cast<f32x4*>(po + (size_t)c*HWn));
        }
    } else {
        const int base0 = iys[0]*Wn + ixs[0];
        const int base1 = iys[1]*Wn + ixs[1];
        const int base2 = iys[2]*Wn + ixs[2];
        const int base3 = iys[3]*Wn + ixs[3];
        #pragma unroll 4
        for (int c = 0; c < Cn; ++c) {
            const float* pc = xb + (size_t)c*HWn;
            const float s = sc[c], t = sh[c];
            f32x4 o;
            o[0] = pc[base0]*s + t;
            o[1] = pc[base1]*s + t;
            o[2] = pc[base2]*s + t;
            o[3] = pc[base3]*s + t;
            __builtin_nontemporal_store(o, reinterpret_cast<f32x4*>(po + (size_t)c*HWn));
        }
    }
}

extern "C" void kernel_launch(void* const* d_in, const int* in_sizes, int n_in,
                              void* d_out, int out_size, void* d_ws, size_t ws_size,
                              hipStream_t stream) {
    const float* x     = (const float*)d_in[0];  // aligned_feat
    const float* wgt   = (const float*)d_in[3];  // gn_weight
    const float* bias  = (const float*)d_in[4];  // gn_bias
    const float* ow    = (const float*)d_in[5];  // offset_w (2,8,3,3)
    const float* ob    = (const float*)d_in[6];  // offset_b (2,)
    const float* sw    = (const float*)d_in[7];  // scale_w
    const float* sb    = (const float*)d_in[8];  // scale_b
    float* out = (float*)d_out;
    float* ws  = (float*)d_ws;

    k_stats1<<<dim3(NGn, NBLKn), 256, 0, stream>>>(x, ws);
    k_stats2<<<NGn, 64, 0, stream>>>(ws);
    k_sim2  <<<448, 256, 0, stream>>>(x, wgt, bias, ws);
    k_csamp <<<(Bn*HWn/4)/256, 256, 0, stream>>>(x, wgt, bias, ow, ob, sw, sb, ws, out);
}

// Round 9
// 61.175 us; speedup vs baseline: 4.5341x; 1.8105x over previous
//
#include <hip/hip_runtime.h>
#include <hip/hip_bf16.h>

// Problem constants
#define Bn   4
#define Cn   64
#define Hn   256
#define Wn   448
#define Gn   8                 // num_groups = C/8
#define CGn  8                 // channels per group
#define HWn  (Hn*Wn)           // 114688
#define CHWn (Cn*HWn)          // 7340032
#define NGn  (Bn*Gn)           // 32 (b,g) pairs
#define NBLKn 32               // row-chunks per (b,g) for stats partials
#define ROWS_PER_BLK (Hn/NBLKn)            // 8
#define ELEMS_PER_BLK (CGn*ROWS_PER_BLK*Wn) // 28672
#define VEC_PER_BLK  (ELEMS_PER_BLK/4)      // 7168 float4
#define VEC_PER_CHUNK ((ROWS_PER_BLK*Wn)/4) // 896 float4 per channel-chunk

typedef float f32x4 __attribute__((ext_vector_type(4)));

// ws layout (float offsets)
#define WS_PART 0                          // 32*32*2 = 2048
#define WS_MEAN 2048                       // 32*2 = 64  (mean, rstd)
#define WS_FLAG 3000                       // 1 float: 1.0 => identity-gather certified
#define WS_RN   4096                       // (unused, kept for layout stability)
#define WS_SIM  (WS_RN + Bn*HWn)           // B*8*HW

// ---------------- stats pass 1: per-(b,g,rowchunk) partial sum/sumsq ----------------
__global__ __launch_bounds__(256) void k_stats1(const float* __restrict__ x,
                                                float* __restrict__ ws) {
    const int bg  = blockIdx.x;       // 0..31
    const int blk = blockIdx.y;       // 0..31
    const int b = bg >> 3, g = bg & 7;
    const int r0 = blk * ROWS_PER_BLK;
    const float4* base = reinterpret_cast<const float4*>(
        x + (size_t)b*CHWn + (size_t)g*CGn*HWn + (size_t)r0*Wn);

    float s = 0.f, sq = 0.f;
    for (int i = threadIdx.x; i < VEC_PER_BLK; i += 256) {
        int ci  = i / VEC_PER_CHUNK;            // channel within group (0..7)
        int rem = i - ci*VEC_PER_CHUNK;
        float4 v = base[(size_t)ci*(HWn/4) + rem];
        s  += v.x + v.y + v.z + v.w;
        sq += v.x*v.x + v.y*v.y + v.z*v.z + v.w*v.w;
    }
    __shared__ float shs[4], shq[4];
    for (int o = 32; o > 0; o >>= 1) { s += __shfl_down(s, o); sq += __shfl_down(sq, o); }
    const int wid = threadIdx.x >> 6;
    if ((threadIdx.x & 63) == 0) { shs[wid] = s; shq[wid] = sq; }
    __syncthreads();
    if (threadIdx.x == 0) {
        s  = shs[0] + shs[1] + shs[2] + shs[3];
        sq = shq[0] + shq[1] + shq[2] + shq[3];
        ws[WS_PART + (bg*NBLKn + blk)*2 + 0] = s;
        ws[WS_PART + (bg*NBLKn + blk)*2 + 1] = sq;
    }
}

// ---------------- stats pass 2 + certificate ----------------
// blocks 0..31: combine partials -> mean, rstd for (b,g)
// block 32: identity-gather certificate from conv weights:
//   |off_k| <= (|ob_k| + sum|ow_k|) * max(sigmoid) * max|sim| <= |ob_k| + sum|ow_k|
//   (|sim|<=1 since cosine, sigmoid<1). If both bounds < 0.499, every gather
//   index round(w+off)==w bit-exactly -> sim/conv pipeline is dead code.
__global__ __launch_bounds__(64) void k_stats2c(float* __restrict__ ws,
                                                const float* __restrict__ ow,
                                                const float* __restrict__ obias) {
    const int bg = blockIdx.x;
    const int t  = threadIdx.x;
    if (bg < NGn) {
        float s = 0.f, sq = 0.f;
        if (t < NBLKn) {
            s  = ws[WS_PART + (bg*NBLKn + t)*2 + 0];
            sq = ws[WS_PART + (bg*NBLKn + t)*2 + 1];
        }
        for (int o = 32; o > 0; o >>= 1) { s += __shfl_down(s, o); sq += __shfl_down(sq, o); }
        if (t == 0) {
            const float n = (float)(CGn*HWn);
            float mean = s / n;
            float var  = sq / n - mean*mean;
            ws[WS_MEAN + bg*2 + 0] = mean;
            ws[WS_MEAN + bg*2 + 1] = 1.0f / sqrtf(var + 1e-5f);
        }
    } else {
        // certificate block
        float s0 = 0.f, s1 = 0.f;
        for (int i = t; i < 72; i += 64) {
            s0 += fabsf(ow[i]);
            s1 += fabsf(ow[72 + i]);
        }
        for (int o = 32; o > 0; o >>= 1) { s0 += __shfl_down(s0, o); s1 += __shfl_down(s1, o); }
        if (t == 0) {
            float B0 = fabsf(obias[0]) + s0;
            float B1 = fabsf(obias[1]) + s1;
            ws[WS_FLAG] = (B0 < 0.499f && B1 < 0.499f) ? 1.0f : 0.0f;
        }
    }
}

// helper: load per-channel affine (scale, shift) into LDS. b uniform per block.
__device__ __forceinline__ void load_affine(const float* __restrict__ ws,
                                            const float* __restrict__ wgt,
                                            const float* __restrict__ bias,
                                            int b, float* sc, float* sh) {
    if (threadIdx.x < Cn) {
        int c = threadIdx.x;
        float mean = ws[WS_MEAN + (b*Gn + (c >> 3))*2 + 0];
        float rstd = ws[WS_MEAN + (b*Gn + (c >> 3))*2 + 1];
        float s = rstd * wgt[c];
        sc[c] = s;
        sh[c] = bias[c] - mean * s;
    }
    __syncthreads();
}

// ---------------- fused norm + cosine similarity, LDS-tiled ----------------
#define S_R4 18                 // float4 per staged row
#define S_ROWS 20
#define NSTG (S_ROWS*S_R4)      // 360 staged float4

#define STAGE_STEP(C, RA, RB, TB)                                              \
    {                                                                          \
        const float s_ = sc[(C)], t_ = sh[(C)];                                \
        float4 wv0, wv1;                                                       \
        wv0.x = val0 ? RA.x*s_ + t_ : 0.f;                                     \
        wv0.y = val0 ? RA.y*s_ + t_ : 0.f;                                     \
        wv0.z = val0 ? RA.z*s_ + t_ : 0.f;                                     \
        wv0.w = val0 ? RA.w*s_ + t_ : 0.f;                                     \
        wv1.x = val1 ? RB.x*s_ + t_ : 0.f;                                     \
        wv1.y = val1 ? RB.y*s_ + t_ : 0.f;                                     \
        wv1.z = val1 ? RB.z*s_ + t_ : 0.f;                                     \
        wv1.w = val1 ? RB.w*s_ + t_ : 0.f;                                     \
        TB[r0c*S_R4 + c40] = wv0;                                              \
        if (has1) TB[r1c*S_R4 + c41] = wv1;                                    \
        a0.x += wv0.x*wv0.x; a0.y += wv0.y*wv0.y;                              \
        a0.z += wv0.z*wv0.z; a0.w += wv0.w*wv0.w;                              \
        a1.x += wv1.x*wv1.x; a1.y += wv1.y*wv1.y;                              \
        a1.z += wv1.z*wv1.z; a1.w += wv1.w*wv1.w;                              \
        if ((C) + 2 < Cn) {                                                    \
            RA = xb[(size_t)((C)+2)*HW4 + off0];                               \
            RB = xb[(size_t)((C)+2)*HW4 + off1];                               \
        }                                                                      \
        __syncthreads();                                                       \
        const float4* tb = TB;                                                 \
        float4 m0 = tb[(prow  )*S_R4 + pc4], m1 = tb[(prow  )*S_R4 + pc4+1],   \
               m2 = tb[(prow  )*S_R4 + pc4+2];                                 \
        float4 z0 = tb[(prow+2)*S_R4 + pc4], z1 = tb[(prow+2)*S_R4 + pc4+1],   \
               z2 = tb[(prow+2)*S_R4 + pc4+2];                                 \
        float4 p0 = tb[(prow+4)*S_R4 + pc4], p1 = tb[(prow+4)*S_R4 + pc4+1],   \
               p2 = tb[(prow+4)*S_R4 + pc4+2];                                 \
        float vm[12] = {m0.x,m0.y,m0.z,m0.w, m1.x,m1.y,m1.z,m1.w,              \
                        m2.x,m2.y,m2.z,m2.w};                                  \
        float vz[12] = {z0.x,z0.y,z0.z,z0.w, z1.x,z1.y,z1.z,z1.w,              \
                        z2.x,z2.y,z2.z,z2.w};                                  \
        float vp[12] = {p0.x,p0.y,p0.z,p0.w, p1.x,p1.y,p1.z,p1.w,              \
                        p2.x,p2.y,p2.z,p2.w};                                  \
        _Pragma("unroll")                                                      \
        for (int j = 0; j < 4; ++j) {                                          \
            float xc = vz[4+j];                                                \
            dot[j][0] += xc*vm[2+j];                                           \
            dot[j][1] += xc*vm[4+j];                                           \
            dot[j][2] += xc*vm[6+j];                                           \
            dot[j][3] += xc*vz[2+j];                                           \
            dot[j][4] += xc*vz[6+j];                                           \
            dot[j][5] += xc*vp[2+j];                                           \
            dot[j][6] += xc*vp[4+j];                                           \
            dot[j][7] += xc*vp[6+j];                                           \
        }                                                                      \
    }

__global__ __launch_bounds__(256) void k_sim2(const float* __restrict__ x,
                                              const float* __restrict__ wgt,
                                              const float* __restrict__ bias,
                                              float* __restrict__ ws) {
    // identity-certified: sim is dead code, exit (uniform branch)
    if (ws[WS_FLAG] != 0.0f) return;

    __shared__ float sc[Cn], sh[Cn];
    __shared__ float4 tile[2][NSTG];
    __shared__ float4 n2s[NSTG];

    // XCD-chunked swizzle: 448 blocks, 56 consecutive (h-adjacent) per XCD
    int lin = blockIdx.x;
    int nid = (lin & 7) * 56 + (lin >> 3);
    int b   = nid / 112;
    int rem = nid - b*112;
    int th_ = rem / 7;
    int tw_ = rem - th_*7;
    const int h0 = th_*16, w0 = tw_*64;

    load_affine(ws, wgt, bias, b, sc, sh);

    const int tid = threadIdx.x;
    const int r0c = tid / S_R4, c40 = tid - r0c*S_R4;
    const int i1  = tid + 256;
    const bool has1 = (i1 < NSTG);
    const int r1c = i1 / S_R4, c41 = i1 - r1c*S_R4;

    const int gr0 = h0 - 2 + r0c, gc0 = (w0 >> 2) - 1 + c40;
    const bool val0 = (gr0 >= 0) & (gr0 < Hn) & (gc0 >= 0) & (gc0 < (Wn/4));
    const int gr1 = h0 - 2 + r1c, gc1 = (w0 >> 2) - 1 + c41;
    const bool val1 = has1 & (gr1 >= 0) & (gr1 < Hn) & (gc1 >= 0) & (gc1 < (Wn/4));

    const float4* xb = reinterpret_cast<const float4*>(x + (size_t)b*CHWn);
    const size_t HW4 = HWn/4;
    const size_t off0 = val0 ? ((size_t)gr0*(Wn/4) + gc0) : 0;
    const size_t off1 = val1 ? ((size_t)gr1*(Wn/4) + gc1) : 0;

    const int prow = tid >> 4;          // 0..15
    const int pc4  = tid & 15;          // 0..15

    float dot[4][8];
    #pragma unroll
    for (int j = 0; j < 4; ++j)
        #pragma unroll
        for (int k = 0; k < 8; ++k) dot[j][k] = 0.f;

    float4 a0 = {0,0,0,0}, a1 = {0,0,0,0};

    // depth-2 prefetch: channels 0 and 1 in flight before the loop
    float4 pa0 = xb[off0],        pb0 = xb[off1];
    float4 pa1 = xb[HW4 + off0],  pb1 = xb[HW4 + off1];

    for (int cc = 0; cc < Cn; cc += 2) {
        STAGE_STEP(cc,     pa0, pb0, tile[0]);
        STAGE_STEP(cc + 1, pa1, pb1, tile[1]);
    }

    n2s[r0c*S_R4 + c40] = a0;
    if (has1) n2s[r1c*S_R4 + c41] = a1;
    __syncthreads();

    {
        const float4* nb = n2s;
        float4 m0 = nb[(prow  )*S_R4 + pc4], m1 = nb[(prow  )*S_R4 + pc4+1], m2 = nb[(prow  )*S_R4 + pc4+2];
        float4 z0 = nb[(prow+2)*S_R4 + pc4], z1 = nb[(prow+2)*S_R4 + pc4+1], z2 = nb[(prow+2)*S_R4 + pc4+2];
        float4 p0 = nb[(prow+4)*S_R4 + pc4], p1 = nb[(prow+4)*S_R4 + pc4+1], p2 = nb[(prow+4)*S_R4 + pc4+2];
        float nm[12] = {m0.x,m0.y,m0.z,m0.w, m1.x,m1.y,m1.z,m1.w, m2.x,m2.y,m2.z,m2.w};
        float nz[12] = {z0.x,z0.y,z0.z,z0.w, z1.x,z1.y,z1.z,z1.w, z2.x,z2.y,z2.z,z2.w};
        float np_[12]= {p0.x,p0.y,p0.z,p0.w, p1.x,p1.y,p1.z,p1.w, p2.x,p2.y,p2.z,p2.w};
        float rm[8], rz[8], rp[8];
        #pragma unroll
        for (int e = 0; e < 8; ++e) {
            rm[e] = 1.0f / fmaxf(sqrtf(nm[2+e]), 1e-8f);
            rz[e] = 1.0f / fmaxf(sqrtf(nz[2+e]), 1e-8f);
            rp[e] = 1.0f / fmaxf(sqrtf(np_[2+e]), 1e-8f);
        }
        float* simb = ws + WS_SIM + (size_t)b*8*HWn + (size_t)(h0+prow)*Wn + (w0 + pc4*4);
        #pragma unroll
        for (int k = 0; k < 8; ++k) {
            f32x4 o;
            #pragma unroll
            for (int j = 0; j < 4; ++j) {
                float rnc = rz[2+j];
                float rnn;
                switch (k) {
                    case 0: rnn = rm[j];   break;
                    case 1: rnn = rm[2+j]; break;
                    case 2: rnn = rm[4+j]; break;
                    case 3: rnn = rz[j];   break;
                    case 4: rnn = rz[4+j]; break;
                    case 5: rnn = rp[j];   break;
                    case 6: rnn = rp[2+j]; break;
                    default: rnn = rp[4+j]; break;
                }
                o[j] = dot[j][k]*rnc*rnn;
            }
            *reinterpret_cast<f32x4*>(simb + (size_t)k*HWn) = o;
        }
    }
}

// ---------------- fused: 3x3 convs + sigmoid gate + nearest-sample + out ----------------
__global__ __launch_bounds__(256) void k_csamp(const float* __restrict__ x,
                                               const float* __restrict__ wgt,
                                               const float* __restrict__ bias,
                                               const float* __restrict__ ow,
                                               const float* __restrict__ obias,
                                               const float* __restrict__ sw,
                                               const float* __restrict__ sbias,
                                               const float* __restrict__ ws,
                                               float* __restrict__ out) {
    __shared__ float sc[Cn], sh[Cn];
    __shared__ float wo[144], wg[144];

    const float flag = ws[WS_FLAG];                // uniform

    const int u  = blockIdx.x*256 + threadIdx.x;   // f4 index in [0, B*HW/4)
    const int b  = u / (HWn/4);
    const int r4 = u - b*(HWn/4);
    const int h  = r4 / (Wn/4);
    const int j  = r4 - h*(Wn/4);                  // f4 col 0..111

    load_affine(ws, wgt, bias, b, sc, sh);         // includes one __syncthreads

    int ixs[4], iys[4];

    if (flag != 0.0f) {
        // certified: every index is identity
        #pragma unroll
        for (int p = 0; p < 4; ++p) { ixs[p] = 4*j + p; iys[p] = h; }
    } else {
        for (int i = threadIdx.x; i < 144; i += 256) { wo[i] = ow[i]; wg[i] = sw[i]; }
        __syncthreads();

        float ao0[4], ao1[4], as0[4], as1[4];
        {
            const float b0 = obias[0], b1 = obias[1], c0 = sbias[0], c1 = sbias[1];
            #pragma unroll
            for (int p = 0; p < 4; ++p) { ao0[p] = b0; ao1[p] = b1; as0[p] = c0; as1[p] = c1; }
        }

        const float* simb = ws + WS_SIM + (size_t)b*8*HWn;
        #pragma unroll 2
        for (int kc = 0; kc < 8; ++kc) {
            const float* sp = simb + (size_t)kc*HWn;
            #pragma unroll
            for (int dy = -1; dy <= 1; ++dy) {
                const int hh = h + dy;
                const bool rowok = (hh >= 0) & (hh < Hn);
                const float* rowp = sp + (size_t)hh*Wn;
                float4 Bv = {0,0,0,0};
                float Aw = 0.f, Cx = 0.f;
                if (rowok) {
                    Bv = reinterpret_cast<const float4*>(rowp)[j];
                    if (j > 0)   Aw = rowp[4*j - 1];
                    if (j < 111) Cx = rowp[4*j + 4];
                }
                float win[6] = {Aw, Bv.x, Bv.y, Bv.z, Bv.w, Cx};
                const int wi = kc*9 + (dy+1)*3;
                const float w00 = wo[wi], w01 = wo[wi+1], w02 = wo[wi+2];
                const float w10 = wo[wi+72], w11 = wo[wi+73], w12 = wo[wi+74];
                const float g00 = wg[wi], g01 = wg[wi+1], g02 = wg[wi+2];
                const float g10 = wg[wi+72], g11 = wg[wi+73], g12 = wg[wi+74];
                #pragma unroll
                for (int p = 0; p < 4; ++p) {
                    const float t0 = win[p], t1 = win[p+1], t2 = win[p+2];
                    ao0[p] += w00*t0 + w01*t1 + w02*t2;
                    ao1[p] += w10*t0 + w11*t1 + w12*t2;
                    as0[p] += g00*t0 + g01*t1 + g02*t2;
                    as1[p] += g10*t0 + g11*t1 + g12*t2;
                }
            }
        }

        // offsets -> nearest indices (exact reference arithmetic, f32)
        #pragma unroll
        for (int p = 0; p < 4; ++p) {
            const float o0 = ao0[p] * (1.0f / (1.0f + expf(-as0[p])));
            const float o1 = ao1[p] * (1.0f / (1.0f + expf(-as1[p])));
            const int w = 4*j + p;
            float gx  = ((float)w + 0.5f) + o0;
            float gy  = ((float)h + 0.5f) + o1;
            float ngx = 2.0f*gx/(float)Wn - 1.0f;
            float ngy = 2.0f*gy/(float)Hn - 1.0f;
            float fx  = ((ngx + 1.0f)*(float)Wn - 1.0f)*0.5f;
            float fy  = ((ngy + 1.0f)*(float)Hn - 1.0f)*0.5f;
            ixs[p] = (int)fminf(fmaxf(rintf(fx), 0.f), (float)(Wn-1));
            iys[p] = (int)fminf(fmaxf(rintf(fy), 0.f), (float)(Hn-1));
        }
    }

    const float* xb = x + (size_t)b*CHWn;
    float* po = out + (size_t)b*CHWn + (size_t)h*Wn + 4*j;

    // Fast path: all 4 gather indices equal this thread's own float4 cell
    const bool fast = (iys[0]==h) & (ixs[0]==4*j  ) &
                      (iys[1]==h) & (ixs[1]==4*j+1) &
                      (iys[2]==h) & (ixs[2]==4*j+2) &
                      (iys[3]==h) & (ixs[3]==4*j+3);
    if (fast) {
        const size_t o = (size_t)h*Wn + 4*j;
        #pragma unroll 8
        for (int c = 0; c < Cn; ++c) {
            const f32x4 v = *reinterpret_cast<const f32x4*>(xb + (size_t)c*HWn + o);
            const float s = sc[c], t = sh[c];
            f32x4 ov;
            ov[0] = v[0]*s + t; ov[1] = v[1]*s + t;
            ov[2] = v[2]*s + t; ov[3] = v[3]*s + t;
            __builtin_nontemporal_store(ov, reinterpret_cast<f32x4*>(po + (size_t)c*HWn));
        }
    } else {
        const int base0 = iys[0]*Wn + ixs[0];
        const int base1 = iys[1]*Wn + ixs[1];
        const int base2 = iys[2]*Wn + ixs[2];
        const int base3 = iys[3]*Wn + ixs[3];
        #pragma unroll 4
        for (int c = 0; c < Cn; ++c) {
            const float* pc = xb + (size_t)c*HWn;
            const float s = sc[c], t = sh[c];
            f32x4 o;
            o[0] = pc[base0]*s + t;
            o[1] = pc[base1]*s + t;
            o[2] = pc[base2]*s + t;
            o[3] = pc[base3]*s + t;
            __builtin_nontemporal_store(o, reinterpret_cast<f32x4*>(po + (size_t)c*HWn));
        }
    }
}

extern "C" void kernel_launch(void* const* d_in, const int* in_sizes, int n_in,
                              void* d_out, int out_size, void* d_ws, size_t ws_size,
                              hipStream_t stream) {
    const float* x     = (const float*)d_in[0];  // aligned_feat
    const float* wgt   = (const float*)d_in[3];  // gn_weight
    const float* bias  = (const float*)d_in[4];  // gn_bias
    const float* ow    = (const float*)d_in[5];  // offset_w (2,8,3,3)
    const float* ob    = (const float*)d_in[6];  // offset_b (2,)
    const float* sw    = (const float*)d_in[7];  // scale_w
    const float* sb    = (const float*)d_in[8];  // scale_b
    float* out = (float*)d_out;
    float* ws  = (float*)d_ws;

    k_stats1 <<<dim3(NGn, NBLKn), 256, 0, stream>>>(x, ws);
    k_stats2c<<<NGn + 1, 64, 0, stream>>>(ws, ow, ob);
    k_sim2   <<<448, 256, 0, stream>>>(x, wgt, bias, ws);
    k_csamp  <<<(Bn*HWn/4)/256, 256, 0, stream>>>(x, wgt, bias, ow, ob, sw, sb, ws, out);
}